// Round 17
// baseline (236.681 us; speedup 1.0000x reference)
//
#include <hip/hip_runtime.h>
#include <hip/hip_bf16.h>
#include <math.h>

// Problem constants
#define Bz 2
#define Tz 2048
#define Cz 1024
#define Hz 16
#define Dz 64      // HEAD_DIM
#define Rz 32      // ROPE_DIM
#define KVR 256
#define QR 512
#define DQK 96     // HEAD_DIM + ROPE_DIM
#define Mz (Bz*Tz)         // 4096 rows
#define BHT (Bz*Hz*Tz)     // 65536
#define QK_SCALE2 0.14724538519399733f // 1/sqrt(96) * log2(e)  (exp2-domain)
#define THR2 11.541560327111707f       // 8 nats in exp2 domain

typedef __attribute__((ext_vector_type(8))) short short8;
typedef __attribute__((ext_vector_type(4))) float f32x4;
typedef __attribute__((ext_vector_type(4))) unsigned short ushort4v;

__device__ __forceinline__ unsigned short f2bf(float f) {
    union { float f; unsigned u; } un; un.f = f;
    unsigned r = un.u + 0x7FFF + ((un.u >> 16) & 1);
    return (unsigned short)(r >> 16);
}

__device__ __forceinline__ void gload_lds16(const void* g, void* l) {
    __builtin_amdgcn_global_load_lds(
        (const __attribute__((address_space(1))) unsigned int*)g,
        (__attribute__((address_space(3))) unsigned int*)l, 16, 0, 0);
}

// ---------------------------------------------------------------------------
// f32 -> bf16 straight convert
// ---------------------------------------------------------------------------
__global__ __launch_bounds__(256) void conv_f32_bf16(const float* __restrict__ in,
                                                     unsigned short* __restrict__ out,
                                                     int n)
{
    int i = (blockIdx.x * 256 + threadIdx.x) * 4;
    if (i >= n) return;
    float4 v = *(const float4*)&in[i];
    ushort4v o = { f2bf(v.x), f2bf(v.y), f2bf(v.z), f2bf(v.w) };
    *(ushort4v*)&out[i] = o;
}

// ---------------------------------------------------------------------------
// ALL weight transposes in one launch. f32 (K x N) -> bf16 (N x K).
// ---------------------------------------------------------------------------
struct TDesc8 {
    const float* src[8];
    unsigned short* dst[8];
    int K[8], N[8];
    int tile0[9];
};

__global__ __launch_bounds__(256) void transpose_all(TDesc8 p)
{
    __shared__ float ts[32][33];
    int t = blockIdx.x;
    int wi = 0;
    #pragma unroll
    for (int i = 0; i < 7; i++) if (t >= p.tile0[i + 1]) wi = i + 1;
    int lt = t - p.tile0[wi];
    int K = p.K[wi], N = p.N[wi];
    int kT = K >> 5;
    int k0 = (lt % kT) * 32, n0 = (lt / kT) * 32;
    const float* in = p.src[wi];
    unsigned short* out = p.dst[wi];

    int tid = threadIdx.x;
    int r = tid >> 5, cc = tid & 31;
    #pragma unroll
    for (int l = 0; l < 4; l++)
        ts[r + l * 8][cc] = in[(size_t)(k0 + r + l * 8) * N + n0 + cc];
    __syncthreads();
    #pragma unroll
    for (int l = 0; l < 4; l++)
        out[(size_t)(n0 + r + l * 8) * K + k0 + cc] = f2bf(ts[cc][r + l * 8]);
}

// ---------------------------------------------------------------------------
// Single-wave MFMA GEMM: block = 64 threads = 1 wave; wave owns a 64x64 output
// tile. global_load_lds staging, wave-private LDS, no barriers.
// EMODE 1: G1 epilogue ranges; EMODE 4: W_o (heads-gather A, fp32 out)
// ---------------------------------------------------------------------------
template<int EMODE>
__global__ __launch_bounds__(64) void gemm1w(
    const unsigned short* __restrict__ A, const unsigned short* __restrict__ Wt,
    void* __restrict__ O0, void* __restrict__ O1, void* __restrict__ O2,
    int K, float scale)
{
    __shared__ __attribute__((aligned(16))) unsigned short As[64 * 64];
    __shared__ __attribute__((aligned(16))) unsigned short Bs[64 * 64];

    const int lane = threadIdx.x;
    const int c = lane & 15, g = lane >> 4;
    const int m0 = blockIdx.x * 64, n0 = blockIdx.y * 64;
    const int rl = lane >> 3, c8 = lane & 7;

    f32x4 acc[4][4] = {};

    auto stage = [&](int k0) {
        if (EMODE == 4) {
            int h = k0 >> 6;
            #pragma unroll
            for (int i = 0; i < 8; i++) {
                int m = m0 + i * 8 + rl;
                int b = m >> 11, t = m & (Tz - 1);
                gload_lds16(&A[(((size_t)b * Hz + h) * Tz + t) * 64 + c8 * 8],
                            &As[(i * 64 + lane) * 8]);
            }
        } else {
            #pragma unroll
            for (int i = 0; i < 8; i++)
                gload_lds16(&A[(size_t)(m0 + i * 8 + rl) * K + k0 + c8 * 8],
                            &As[(i * 64 + lane) * 8]);
        }
        #pragma unroll
        for (int i = 0; i < 8; i++)
            gload_lds16(&Wt[(size_t)(n0 + i * 8 + rl) * K + k0 + c8 * 8],
                        &Bs[(i * 64 + lane) * 8]);
    };

    stage(0);

    for (int k0 = 0; k0 < K; k0 += 64) {
        asm volatile("s_waitcnt vmcnt(0)" ::: "memory");
        __builtin_amdgcn_sched_barrier(0);

        short8 af[2][4], bfr[2][4];
        #pragma unroll
        for (int ks = 0; ks < 2; ks++) {
            #pragma unroll
            for (int mq = 0; mq < 4; mq++)
                af[ks][mq] = *(const short8*)&As[(mq * 16 + c) * 64 + ks * 32 + g * 8];
            #pragma unroll
            for (int nt = 0; nt < 4; nt++)
                bfr[ks][nt] = *(const short8*)&Bs[(nt * 16 + c) * 64 + ks * 32 + g * 8];
        }
        asm volatile("s_waitcnt lgkmcnt(0)" ::: "memory");
        __builtin_amdgcn_sched_barrier(0);

        if (k0 + 64 < K) stage(k0 + 64);

        __builtin_amdgcn_s_setprio(1);
        #pragma unroll
        for (int ks = 0; ks < 2; ks++)
            #pragma unroll
            for (int mq = 0; mq < 4; mq++)
                #pragma unroll
                for (int nt = 0; nt < 4; nt++)
                    acc[mq][nt] = __builtin_amdgcn_mfma_f32_16x16x32_bf16(
                        af[ks][mq], bfr[ks][nt], acc[mq][nt], 0, 0, 0);
        __builtin_amdgcn_s_setprio(0);
    }

    #pragma unroll
    for (int mq = 0; mq < 4; mq++) {
        #pragma unroll
        for (int r = 0; r < 4; r++) {
            int m = m0 + mq * 16 + g * 4 + r;
            int b = m >> 11, t = m & (Tz - 1);

            if (EMODE == 1) {
                if (n0 < 256) {
                    #pragma unroll
                    for (int nt = 0; nt < 4; nt++)
                        ((float*)O0)[(size_t)m * 256 + n0 + nt * 16 + c] = acc[mq][nt][r];
                } else if (n0 < 768) {
                    #pragma unroll
                    for (int nt = 0; nt < 4; nt++)
                        ((unsigned short*)O1)[(size_t)m * 512 + (n0 - 256) + nt * 16 + c] =
                            f2bf(acc[mq][nt][r]);
                } else {
                    float inv = __expf(-(float)c * 0.5756462732485114f);
                    float ang = (float)t * inv;
                    float cs = cosf(ang), sn = sinf(ang);
                    #pragma unroll
                    for (int np = 0; np < 4; np += 2) {
                        float v0 = acc[mq][np][r];
                        float v1 = acc[mq][np + 1][r];
                        int col0 = (n0 - 768) + np * 16;
                        int h = col0 >> 5;
                        size_t base = (((size_t)b * Hz + h) * Tz + t) * DQK + 64;
                        ((unsigned short*)O2)[base + c]      = f2bf(v0 * cs - v1 * sn);
                        ((unsigned short*)O2)[base + c + 16] = f2bf(v1 * cs + v0 * sn);
                    }
                }
            } else { // EMODE 4
                #pragma unroll
                for (int nt = 0; nt < 4; nt++)
                    ((float*)O0)[(size_t)m * 1024 + n0 + nt * 16 + c] = acc[mq][nt][r];
            }
        }
    }
}

// ---------------------------------------------------------------------------
// Merged G2 (q decode, N=1536, K=512) + G3 (kv decode, N=2048, K=256).
// ---------------------------------------------------------------------------
__global__ __launch_bounds__(64) void gemm1w23(
    const unsigned short* __restrict__ A2, const unsigned short* __restrict__ W2,
    unsigned short* __restrict__ qbb,
    const unsigned short* __restrict__ A3, const unsigned short* __restrict__ W3,
    unsigned short* __restrict__ kbb, unsigned short* __restrict__ vtb)
{
    const bool is2 = blockIdx.y < 24;
    const unsigned short* A  = is2 ? A2 : A3;
    const unsigned short* Wt = is2 ? W2 : W3;
    const int K = is2 ? QR : KVR;
    const int n0 = (is2 ? blockIdx.y : (blockIdx.y - 24)) * 64;

    __shared__ __attribute__((aligned(16))) unsigned short As[64 * 64];
    __shared__ __attribute__((aligned(16))) unsigned short Bs[64 * 64];

    const int lane = threadIdx.x;
    const int c = lane & 15, g = lane >> 4;
    const int m0 = blockIdx.x * 64;
    const int rl = lane >> 3, c8 = lane & 7;

    f32x4 acc[4][4] = {};

    auto stage = [&](int k0) {
        #pragma unroll
        for (int i = 0; i < 8; i++)
            gload_lds16(&A[(size_t)(m0 + i * 8 + rl) * K + k0 + c8 * 8],
                        &As[(i * 64 + lane) * 8]);
        #pragma unroll
        for (int i = 0; i < 8; i++)
            gload_lds16(&Wt[(size_t)(n0 + i * 8 + rl) * K + k0 + c8 * 8],
                        &Bs[(i * 64 + lane) * 8]);
    };

    stage(0);

    for (int k0 = 0; k0 < K; k0 += 64) {
        asm volatile("s_waitcnt vmcnt(0)" ::: "memory");
        __builtin_amdgcn_sched_barrier(0);

        short8 af[2][4], bfr[2][4];
        #pragma unroll
        for (int ks = 0; ks < 2; ks++) {
            #pragma unroll
            for (int mq = 0; mq < 4; mq++)
                af[ks][mq] = *(const short8*)&As[(mq * 16 + c) * 64 + ks * 32 + g * 8];
            #pragma unroll
            for (int nt = 0; nt < 4; nt++)
                bfr[ks][nt] = *(const short8*)&Bs[(nt * 16 + c) * 64 + ks * 32 + g * 8];
        }
        asm volatile("s_waitcnt lgkmcnt(0)" ::: "memory");
        __builtin_amdgcn_sched_barrier(0);

        if (k0 + 64 < K) stage(k0 + 64);

        __builtin_amdgcn_s_setprio(1);
        #pragma unroll
        for (int ks = 0; ks < 2; ks++)
            #pragma unroll
            for (int mq = 0; mq < 4; mq++)
                #pragma unroll
                for (int nt = 0; nt < 4; nt++)
                    acc[mq][nt] = __builtin_amdgcn_mfma_f32_16x16x32_bf16(
                        af[ks][mq], bfr[ks][nt], acc[mq][nt], 0, 0, 0);
        __builtin_amdgcn_s_setprio(0);
    }

    #pragma unroll
    for (int mq = 0; mq < 4; mq++) {
        #pragma unroll
        for (int r = 0; r < 4; r++) {
            int m = m0 + mq * 16 + g * 4 + r;
            int b = m >> 11, t = m & (Tz - 1);
            if (is2) {
                if (n0 < 1024) {
                    #pragma unroll
                    for (int nt = 0; nt < 4; nt++) {
                        int n = n0 + nt * 16 + c;
                        int h = n >> 6, dd = n & 63;
                        ((unsigned short*)qbb)[(((size_t)b * Hz + h) * Tz + t) * DQK + dd] =
                            f2bf(acc[mq][nt][r] * QK_SCALE2);
                    }
                } else {
                    float inv = __expf(-(float)c * 0.5756462732485114f);
                    float ang = (float)t * inv;
                    float cs = cosf(ang), sn = sinf(ang);
                    #pragma unroll
                    for (int np = 0; np < 4; np += 2) {
                        float v0 = acc[mq][np][r] * QK_SCALE2;
                        float v1 = acc[mq][np + 1][r] * QK_SCALE2;
                        int col0 = (n0 - 1024) + np * 16;
                        int h = col0 >> 5;
                        size_t base = (((size_t)b * Hz + h) * Tz + t) * DQK + 64;
                        qbb[base + c]      = f2bf(v0 * cs - v1 * sn);
                        qbb[base + c + 16] = f2bf(v1 * cs + v0 * sn);
                    }
                }
            } else {
                if (n0 < 1024) {
                    #pragma unroll
                    for (int nt = 0; nt < 4; nt++) {
                        int n = n0 + nt * 16 + c;
                        int h = n >> 6, dd = n & 63;
                        kbb[(((size_t)b * Hz + h) * Tz + t) * DQK + dd] = f2bf(acc[mq][nt][r]);
                    }
                } else {
                    #pragma unroll
                    for (int nt = 0; nt < 4; nt++) {
                        int n = (n0 - 1024) + nt * 16 + c;
                        int h = n >> 6, dd = n & 63;
                        vtb[(((size_t)b * Hz + h) * 64 + dd) * Tz + t] = f2bf(acc[mq][nt][r]);
                    }
                }
            }
        }
    }
}

// ---------------------------------------------------------------------------
// RMSNorm over rows of 256: fp32 in, bf16 out, gain g. One wave per row.
// ---------------------------------------------------------------------------
__global__ __launch_bounds__(256) void rmsnorm_k(const float* __restrict__ kv,
                                                 const float* __restrict__ g,
                                                 unsigned short* __restrict__ outb)
{
    int row = blockIdx.x * 4 + (threadIdx.x >> 6);
    int lane = threadIdx.x & 63;
    const float* p = kv + (size_t)row * 256;
    float v[4];
    float ss = 0.f;
    #pragma unroll
    for (int i = 0; i < 4; i++) { v[i] = p[lane + i * 64]; ss += v[i] * v[i]; }
    #pragma unroll
    for (int o = 32; o > 0; o >>= 1) ss += __shfl_xor(ss, o);
    float r = rsqrtf(ss * (1.f / 256.f) + 1e-6f);
    #pragma unroll
    for (int i = 0; i < 4; i++)
        outb[(size_t)row * 256 + lane + i * 64] = f2bf(v[i] * r * g[lane + i * 64]);
}

// ---------------------------------------------------------------------------
// FULLY-DECOUPLED single-wave flash attention.
// One 64-lane wave per 16-row q-strip (4096 blocks); NO __syncthreads, NO
// K-staging LDS. K fragments are read from L2 in fragment layout (r4-proven
// addressing) and REFILLED right after the QK MFMAs consume them, so the
// softmax+PV phase (~2000 cyc) hides L2 latency (T14 issue-early). V issued
// early as before. Only LDS: wave-private 2.3KB P strip (wave_barrier only).
// 12 independent waves/CU at uncorrelated phases fill each SIMD.
// ---------------------------------------------------------------------------
#define PSTR 72

__global__ __launch_bounds__(64, 3) void attn_mfma(
    const unsigned short* __restrict__ q,
    const unsigned short* __restrict__ k,
    const unsigned short* __restrict__ vt,
    unsigned short* __restrict__ o)
{
    __shared__ __attribute__((aligned(16))) unsigned short Ps[16 * PSTR];

    int lane = threadIdx.x;
    int c = lane & 15, g = lane >> 4;

    int i = blockIdx.x;                 // 0..4095
    int bh = i & 31;                    // spread across XCDs
    int s = 127 - (i >> 5);             // strip 0..127, longest first
    int q0 = s * 16;
    int ntiles = (s >> 2) + 1;
    int qrem = (s & 3) * 16 + c;        // local q row within diagonal tile

    const unsigned short* qb = q + (size_t)bh * Tz * DQK;
    const unsigned short* kb = k + (size_t)bh * Tz * DQK;
    const unsigned short* vb = vt + (size_t)bh * 64 * Tz;

    // Q fragments (B operand)
    short8 qf[3];
    {
        const unsigned short* qrow = qb + (size_t)(q0 + c) * DQK;
        #pragma unroll
        for (int kc = 0; kc < 3; kc++)
            qf[kc] = *(const short8*)(qrow + kc * 32 + g * 8);
    }

    // fragment offsets (u16 units)
    size_t kfo[3][4], vfo[2][4];
    #pragma unroll
    for (int kc = 0; kc < 3; kc++)
        #pragma unroll
        for (int nt = 0; nt < 4; nt++)
            kfo[kc][nt] = (size_t)(nt * 16 + c) * DQK + kc * 32 + g * 8;
    #pragma unroll
    for (int kc2 = 0; kc2 < 2; kc2++)
        #pragma unroll
        for (int nt = 0; nt < 4; nt++)
            vfo[kc2][nt] = (size_t)(nt * 16 + c) * Tz + kc2 * 32 + g * 8;

    // load tile-0 K and V fragments
    short8 kf[3][4], vf[2][4];
    #pragma unroll
    for (int kc = 0; kc < 3; kc++)
        #pragma unroll
        for (int nt = 0; nt < 4; nt++)
            kf[kc][nt] = *(const short8*)&kb[kfo[kc][nt]];
    #pragma unroll
    for (int kc2 = 0; kc2 < 2; kc2++)
        #pragma unroll
        for (int nt = 0; nt < 4; nt++)
            vf[kc2][nt] = *(const short8*)&vb[vfo[kc2][nt]];

    f32x4 oacc[4] = {};
    float mrun = -1e30f, lrun = 0.f;

    for (int t = 0; t < ntiles; t++) {
        bool more = (t + 1) < ntiles;
        size_t knext = (size_t)(t + 1) * (64 * DQK);
        size_t vnext = (size_t)(t + 1) * 64;

        // S^T = K @ Q^T (fragments already in regs)
        f32x4 sacc[4] = {};
        __builtin_amdgcn_s_setprio(1);
        #pragma unroll
        for (int kc = 0; kc < 3; kc++)
            #pragma unroll
            for (int nt = 0; nt < 4; nt++)
                sacc[nt] = __builtin_amdgcn_mfma_f32_16x16x32_bf16(kf[kc][nt], qf[kc], sacc[nt], 0, 0, 0);
        __builtin_amdgcn_s_setprio(0);

        // refill kf for tile t+1 NOW — latency hides under softmax+PV below
        if (more) {
            #pragma unroll
            for (int kc = 0; kc < 3; kc++)
                #pragma unroll
                for (int nt = 0; nt < 4; nt++)
                    kf[kc][nt] = *(const short8*)&kb[knext + kfo[kc][nt]];
        }

        // causal mask (last tile): k_loc = nt*16+g*4+r vs qrem
        if (t == ntiles - 1) {
            #pragma unroll
            for (int nt = 0; nt < 4; nt++)
                #pragma unroll
                for (int r = 0; r < 4; r++)
                    if (nt * 16 + g * 4 + r > qrem)
                        sacc[nt][r] = -1e30f;
        }

        // row max (lane's q-row = c)
        float pm = sacc[0][0];
        #pragma unroll
        for (int nt = 0; nt < 4; nt++)
            #pragma unroll
            for (int r = 0; r < 4; r++)
                pm = fmaxf(pm, sacc[nt][r]);
        pm = fmaxf(pm, __shfl_xor(pm, 16));
        pm = fmaxf(pm, __shfl_xor(pm, 32));

        bool need = pm > mrun + THR2;
        if (__ballot(need)) {
            float mn = fmaxf(mrun, pm);
            float sc = exp2f(mrun - mn);
            mrun = mn;
            float rs = 0.f;
            #pragma unroll
            for (int nt = 0; nt < 4; nt++)
                #pragma unroll
                for (int r = 0; r < 4; r++) {
                    sacc[nt][r] = exp2f(sacc[nt][r] - mrun);
                    rs += sacc[nt][r];
                }
            rs += __shfl_xor(rs, 16);
            rs += __shfl_xor(rs, 32);
            lrun = lrun * sc + rs;
            float scr[4];
            #pragma unroll
            for (int r = 0; r < 4; r++) scr[r] = __shfl(sc, g * 4 + r);
            #pragma unroll
            for (int nt = 0; nt < 4; nt++)
                #pragma unroll
                for (int r = 0; r < 4; r++)
                    oacc[nt][r] *= scr[r];
        } else {
            float rs = 0.f;
            #pragma unroll
            for (int nt = 0; nt < 4; nt++)
                #pragma unroll
                for (int r = 0; r < 4; r++) {
                    sacc[nt][r] = exp2f(sacc[nt][r] - mrun);
                    rs += sacc[nt][r];
                }
            rs += __shfl_xor(rs, 16);
            rs += __shfl_xor(rs, 32);
            lrun += rs;
        }

        // P -> wave-private LDS strip (cvt_pk pairs)
        #pragma unroll
        for (int nt = 0; nt < 4; nt++)
            #pragma unroll
            for (int rp = 0; rp < 2; rp++) {
                unsigned w32;
                asm("v_cvt_pk_bf16_f32 %0, %1, %2"
                    : "=v"(w32) : "v"(sacc[nt][2 * rp]), "v"(sacc[nt][2 * rp + 1]));
                *(unsigned*)&Ps[c * PSTR + nt * 16 + g * 4 + 2 * rp] = w32;
            }
        __builtin_amdgcn_wave_barrier();

        // O += P @ V (vf in regs since last tile's issue)
        __builtin_amdgcn_s_setprio(1);
        #pragma unroll
        for (int kc2 = 0; kc2 < 2; kc2++) {
            short8 pf = *(const short8*)&Ps[c * PSTR + kc2 * 32 + g * 8];
            #pragma unroll
            for (int nt = 0; nt < 4; nt++)
                oacc[nt] = __builtin_amdgcn_mfma_f32_16x16x32_bf16(pf, vf[kc2][nt], oacc[nt], 0, 0, 0);
        }
        __builtin_amdgcn_s_setprio(0);
        __builtin_amdgcn_wave_barrier();

        // refill vf for tile t+1 — hides under next QK + softmax
        if (more) {
            #pragma unroll
            for (int kc2 = 0; kc2 < 2; kc2++)
                #pragma unroll
                for (int nt = 0; nt < 4; nt++)
                    vf[kc2][nt] = *(const short8*)&vb[vnext + vfo[kc2][nt]];
        }
    }

    // epilogue: fetch per-row l from owner lanes, write bf16 heads buffer
    float lr[4];
    #pragma unroll
    for (int r = 0; r < 4; r++) lr[r] = __shfl(lrun, g * 4 + r);
    #pragma unroll
    for (int nt = 0; nt < 4; nt++)
        #pragma unroll
        for (int r = 0; r < 4; r++)
            o[((size_t)bh * Tz + q0 + g * 4 + r) * 64 + nt * 16 + c] =
                f2bf(oacc[nt][r] / lr[r]);
}

// ---------------------------------------------------------------------------
extern "C" void kernel_launch(void* const* d_in, const int* in_sizes, int n_in,
                              void* d_out, int out_size, void* d_ws, size_t ws_size,
                              hipStream_t stream)
{
    const float* x       = (const float*)d_in[0];
    const float* W_kv    = (const float*)d_in[1];
    const float* g_kv    = (const float*)d_in[2];
    const float* W_kdec  = (const float*)d_in[3];
    const float* W_vdec  = (const float*)d_in[4];
    const float* W_q     = (const float*)d_in[5];
    const float* W_qdec  = (const float*)d_in[6];
    const float* W_krope = (const float*)d_in[7];
    const float* W_qrope = (const float*)d_in[8];
    const float* W_o     = (const float*)d_in[9];
    float* out = (float*)d_out;

    float* kv_f32 = (float*)d_ws;                           // 4096*256 f32
    unsigned short* us = (unsigned short*)(kv_f32 + (size_t)Mz * KVR);
    unsigned short* x_bf  = us;               us += (size_t)Mz * Cz;
    unsigned short* kv_bf = us;               us += (size_t)Mz * KVR;
    unsigned short* qc_bf = us;               us += (size_t)Mz * QR;
    unsigned short* qbb   = us;               us += (size_t)BHT * DQK;
    unsigned short* kbb   = us;               us += (size_t)BHT * DQK;
    unsigned short* vtb   = us;               us += (size_t)BHT * 64;
    unsigned short* ob    = us;               us += (size_t)BHT * 64;
    unsigned short* wc1 = us;                 us += (size_t)1280 * Cz;  // [W_kv|W_q|W_krope]^T
    unsigned short* wc2 = us;                 us += (size_t)1536 * QR;  // [W_qdec|W_qrope]^T
    unsigned short* wc3 = us;                 us += (size_t)2048 * KVR; // [W_kdec|W_vdec]^T
    unsigned short* woT = us;                 us += (size_t)Cz * Cz;    // W_o^T

    dim3 blk(256);

    conv_f32_bf16<<<dim3((Mz*Cz)/1024), blk, 0, stream>>>(x, x_bf, Mz*Cz);

    TDesc8 td;
    const float* tsrc[8] = {W_kv, W_q, W_krope, W_qdec, W_qrope, W_kdec, W_vdec, W_o};
    unsigned short* tdst[8] = {
        wc1, wc1 + (size_t)256 * Cz, wc1 + (size_t)768 * Cz,
        wc2, wc2 + (size_t)1024 * QR,
        wc3, wc3 + (size_t)1024 * KVR,
        woT };
    int tK[8] = {Cz, Cz, Cz, QR, QR, KVR, KVR, Cz};
    int tN[8] = {KVR, QR, Hz*Rz, Hz*Dz, Hz*Rz, Hz*Dz, Hz*Dz, Cz};
    int cum = 0;
    td.tile0[0] = 0;
    for (int i = 0; i < 8; i++) {
        td.src[i] = tsrc[i]; td.dst[i] = tdst[i]; td.K[i] = tK[i]; td.N[i] = tN[i];
        cum += (tK[i] / 32) * (tN[i] / 32);
        td.tile0[i + 1] = cum;
    }
    transpose_all<<<dim3(cum), blk, 0, stream>>>(td);

    // G1: x @ [W_kv | W_q | W_krope]  (N=1280, K=1024)
    gemm1w<1><<<dim3(Mz/64, 1280/64), dim3(64), 0, stream>>>(
        x_bf, wc1, kv_f32, qc_bf, kbb, Cz, 1.f);
    // RMSNorm -> bf16
    rmsnorm_k<<<dim3(Mz/4), blk, 0, stream>>>(kv_f32, g_kv, kv_bf);
    // G2+G3 merged (q decode + kv decode)
    gemm1w23<<<dim3(Mz/64, 56), dim3(64), 0, stream>>>(
        qc_bf, wc2, qbb, kv_bf, wc3, kbb, vtb);
    // Fully-decoupled single-wave flash attention -> bf16 heads buffer
    attn_mfma<<<dim3(4096), dim3(64), 0, stream>>>(qbb, kbb, vtb, ob);
    // G4: heads(ob) @ W_o -> out fp32 (N=1024, K=1024)
    gemm1w<4><<<dim3(Mz/64, Cz/64), dim3(64), 0, stream>>>(
        ob, woT, out, nullptr, nullptr, Cz, 1.f);
}

// Round 18
// 163.238 us; speedup vs baseline: 1.4499x; 1.4499x over previous
//
#include <hip/hip_runtime.h>
#include <hip/hip_bf16.h>
#include <math.h>

// Problem constants
#define Bz 2
#define Tz 2048
#define Cz 1024
#define Hz 16
#define Dz 64      // HEAD_DIM
#define Rz 32      // ROPE_DIM
#define KVR 256
#define QR 512
#define DQK 96     // HEAD_DIM + ROPE_DIM
#define Mz (Bz*Tz)         // 4096 rows
#define BHT (Bz*Hz*Tz)     // 65536
#define QK_SCALE2 0.14724538519399733f // 1/sqrt(96) * log2(e)  (exp2-domain)
#define THR2 11.541560327111707f       // 8 nats in exp2 domain

typedef __attribute__((ext_vector_type(8))) short short8;
typedef __attribute__((ext_vector_type(4))) float f32x4;
typedef __attribute__((ext_vector_type(4))) unsigned short ushort4v;

__device__ __forceinline__ unsigned short f2bf(float f) {
    union { float f; unsigned u; } un; un.f = f;
    unsigned r = un.u + 0x7FFF + ((un.u >> 16) & 1);
    return (unsigned short)(r >> 16);
}

__device__ __forceinline__ void gload_lds16(const void* g, void* l) {
    __builtin_amdgcn_global_load_lds(
        (const __attribute__((address_space(1))) unsigned int*)g,
        (__attribute__((address_space(3))) unsigned int*)l, 16, 0, 0);
}

// ---------------------------------------------------------------------------
// f32 -> bf16 straight convert
// ---------------------------------------------------------------------------
__global__ __launch_bounds__(256) void conv_f32_bf16(const float* __restrict__ in,
                                                     unsigned short* __restrict__ out,
                                                     int n)
{
    int i = (blockIdx.x * 256 + threadIdx.x) * 4;
    if (i >= n) return;
    float4 v = *(const float4*)&in[i];
    ushort4v o = { f2bf(v.x), f2bf(v.y), f2bf(v.z), f2bf(v.w) };
    *(ushort4v*)&out[i] = o;
}

// ---------------------------------------------------------------------------
// ALL weight transposes in one launch. f32 (K x N) -> bf16 (N x K).
// ---------------------------------------------------------------------------
struct TDesc8 {
    const float* src[8];
    unsigned short* dst[8];
    int K[8], N[8];
    int tile0[9];
};

__global__ __launch_bounds__(256) void transpose_all(TDesc8 p)
{
    __shared__ float ts[32][33];
    int t = blockIdx.x;
    int wi = 0;
    #pragma unroll
    for (int i = 0; i < 7; i++) if (t >= p.tile0[i + 1]) wi = i + 1;
    int lt = t - p.tile0[wi];
    int K = p.K[wi], N = p.N[wi];
    int kT = K >> 5;
    int k0 = (lt % kT) * 32, n0 = (lt / kT) * 32;
    const float* in = p.src[wi];
    unsigned short* out = p.dst[wi];

    int tid = threadIdx.x;
    int r = tid >> 5, cc = tid & 31;
    #pragma unroll
    for (int l = 0; l < 4; l++)
        ts[r + l * 8][cc] = in[(size_t)(k0 + r + l * 8) * N + n0 + cc];
    __syncthreads();
    #pragma unroll
    for (int l = 0; l < 4; l++)
        out[(size_t)(n0 + r + l * 8) * K + k0 + cc] = f2bf(ts[cc][r + l * 8]);
}

// ---------------------------------------------------------------------------
// Single-wave MFMA GEMM: block = 64 threads = 1 wave; wave owns a 64x64 output
// tile. global_load_lds staging, wave-private LDS, no barriers.
// EMODE 1: G1 epilogue ranges; EMODE 4: W_o (heads-gather A, fp32 out)
// ---------------------------------------------------------------------------
template<int EMODE>
__global__ __launch_bounds__(64) void gemm1w(
    const unsigned short* __restrict__ A, const unsigned short* __restrict__ Wt,
    void* __restrict__ O0, void* __restrict__ O1, void* __restrict__ O2,
    int K, float scale)
{
    __shared__ __attribute__((aligned(16))) unsigned short As[64 * 64];
    __shared__ __attribute__((aligned(16))) unsigned short Bs[64 * 64];

    const int lane = threadIdx.x;
    const int c = lane & 15, g = lane >> 4;
    const int m0 = blockIdx.x * 64, n0 = blockIdx.y * 64;
    const int rl = lane >> 3, c8 = lane & 7;

    f32x4 acc[4][4] = {};

    auto stage = [&](int k0) {
        if (EMODE == 4) {
            int h = k0 >> 6;
            #pragma unroll
            for (int i = 0; i < 8; i++) {
                int m = m0 + i * 8 + rl;
                int b = m >> 11, t = m & (Tz - 1);
                gload_lds16(&A[(((size_t)b * Hz + h) * Tz + t) * 64 + c8 * 8],
                            &As[(i * 64 + lane) * 8]);
            }
        } else {
            #pragma unroll
            for (int i = 0; i < 8; i++)
                gload_lds16(&A[(size_t)(m0 + i * 8 + rl) * K + k0 + c8 * 8],
                            &As[(i * 64 + lane) * 8]);
        }
        #pragma unroll
        for (int i = 0; i < 8; i++)
            gload_lds16(&Wt[(size_t)(n0 + i * 8 + rl) * K + k0 + c8 * 8],
                        &Bs[(i * 64 + lane) * 8]);
    };

    stage(0);

    for (int k0 = 0; k0 < K; k0 += 64) {
        asm volatile("s_waitcnt vmcnt(0)" ::: "memory");
        __builtin_amdgcn_sched_barrier(0);

        short8 af[2][4], bfr[2][4];
        #pragma unroll
        for (int ks = 0; ks < 2; ks++) {
            #pragma unroll
            for (int mq = 0; mq < 4; mq++)
                af[ks][mq] = *(const short8*)&As[(mq * 16 + c) * 64 + ks * 32 + g * 8];
            #pragma unroll
            for (int nt = 0; nt < 4; nt++)
                bfr[ks][nt] = *(const short8*)&Bs[(nt * 16 + c) * 64 + ks * 32 + g * 8];
        }
        asm volatile("s_waitcnt lgkmcnt(0)" ::: "memory");
        __builtin_amdgcn_sched_barrier(0);

        if (k0 + 64 < K) stage(k0 + 64);

        __builtin_amdgcn_s_setprio(1);
        #pragma unroll
        for (int ks = 0; ks < 2; ks++)
            #pragma unroll
            for (int mq = 0; mq < 4; mq++)
                #pragma unroll
                for (int nt = 0; nt < 4; nt++)
                    acc[mq][nt] = __builtin_amdgcn_mfma_f32_16x16x32_bf16(
                        af[ks][mq], bfr[ks][nt], acc[mq][nt], 0, 0, 0);
        __builtin_amdgcn_s_setprio(0);
    }

    #pragma unroll
    for (int mq = 0; mq < 4; mq++) {
        #pragma unroll
        for (int r = 0; r < 4; r++) {
            int m = m0 + mq * 16 + g * 4 + r;
            int b = m >> 11, t = m & (Tz - 1);

            if (EMODE == 1) {
                if (n0 < 256) {
                    #pragma unroll
                    for (int nt = 0; nt < 4; nt++)
                        ((float*)O0)[(size_t)m * 256 + n0 + nt * 16 + c] = acc[mq][nt][r];
                } else if (n0 < 768) {
                    #pragma unroll
                    for (int nt = 0; nt < 4; nt++)
                        ((unsigned short*)O1)[(size_t)m * 512 + (n0 - 256) + nt * 16 + c] =
                            f2bf(acc[mq][nt][r]);
                } else {
                    float inv = __expf(-(float)c * 0.5756462732485114f);
                    float ang = (float)t * inv;
                    float cs = cosf(ang), sn = sinf(ang);
                    #pragma unroll
                    for (int np = 0; np < 4; np += 2) {
                        float v0 = acc[mq][np][r];
                        float v1 = acc[mq][np + 1][r];
                        int col0 = (n0 - 768) + np * 16;
                        int h = col0 >> 5;
                        size_t base = (((size_t)b * Hz + h) * Tz + t) * DQK + 64;
                        ((unsigned short*)O2)[base + c]      = f2bf(v0 * cs - v1 * sn);
                        ((unsigned short*)O2)[base + c + 16] = f2bf(v1 * cs + v0 * sn);
                    }
                }
            } else { // EMODE 4
                #pragma unroll
                for (int nt = 0; nt < 4; nt++)
                    ((float*)O0)[(size_t)m * 1024 + n0 + nt * 16 + c] = acc[mq][nt][r];
            }
        }
    }
}

// ---------------------------------------------------------------------------
// Merged G2 (q decode, N=1536, K=512) + G3 (kv decode, N=2048, K=256).
// ---------------------------------------------------------------------------
__global__ __launch_bounds__(64) void gemm1w23(
    const unsigned short* __restrict__ A2, const unsigned short* __restrict__ W2,
    unsigned short* __restrict__ qbb,
    const unsigned short* __restrict__ A3, const unsigned short* __restrict__ W3,
    unsigned short* __restrict__ kbb, unsigned short* __restrict__ vtb)
{
    const bool is2 = blockIdx.y < 24;
    const unsigned short* A  = is2 ? A2 : A3;
    const unsigned short* Wt = is2 ? W2 : W3;
    const int K = is2 ? QR : KVR;
    const int n0 = (is2 ? blockIdx.y : (blockIdx.y - 24)) * 64;

    __shared__ __attribute__((aligned(16))) unsigned short As[64 * 64];
    __shared__ __attribute__((aligned(16))) unsigned short Bs[64 * 64];

    const int lane = threadIdx.x;
    const int c = lane & 15, g = lane >> 4;
    const int m0 = blockIdx.x * 64;
    const int rl = lane >> 3, c8 = lane & 7;

    f32x4 acc[4][4] = {};

    auto stage = [&](int k0) {
        #pragma unroll
        for (int i = 0; i < 8; i++)
            gload_lds16(&A[(size_t)(m0 + i * 8 + rl) * K + k0 + c8 * 8],
                        &As[(i * 64 + lane) * 8]);
        #pragma unroll
        for (int i = 0; i < 8; i++)
            gload_lds16(&Wt[(size_t)(n0 + i * 8 + rl) * K + k0 + c8 * 8],
                        &Bs[(i * 64 + lane) * 8]);
    };

    stage(0);

    for (int k0 = 0; k0 < K; k0 += 64) {
        asm volatile("s_waitcnt vmcnt(0)" ::: "memory");
        __builtin_amdgcn_sched_barrier(0);

        short8 af[2][4], bfr[2][4];
        #pragma unroll
        for (int ks = 0; ks < 2; ks++) {
            #pragma unroll
            for (int mq = 0; mq < 4; mq++)
                af[ks][mq] = *(const short8*)&As[(mq * 16 + c) * 64 + ks * 32 + g * 8];
            #pragma unroll
            for (int nt = 0; nt < 4; nt++)
                bfr[ks][nt] = *(const short8*)&Bs[(nt * 16 + c) * 64 + ks * 32 + g * 8];
        }
        asm volatile("s_waitcnt lgkmcnt(0)" ::: "memory");
        __builtin_amdgcn_sched_barrier(0);

        if (k0 + 64 < K) stage(k0 + 64);

        __builtin_amdgcn_s_setprio(1);
        #pragma unroll
        for (int ks = 0; ks < 2; ks++)
            #pragma unroll
            for (int mq = 0; mq < 4; mq++)
                #pragma unroll
                for (int nt = 0; nt < 4; nt++)
                    acc[mq][nt] = __builtin_amdgcn_mfma_f32_16x16x32_bf16(
                        af[ks][mq], bfr[ks][nt], acc[mq][nt], 0, 0, 0);
        __builtin_amdgcn_s_setprio(0);
    }

    #pragma unroll
    for (int mq = 0; mq < 4; mq++) {
        #pragma unroll
        for (int r = 0; r < 4; r++) {
            int m = m0 + mq * 16 + g * 4 + r;
            int b = m >> 11, t = m & (Tz - 1);
            if (is2) {
                if (n0 < 1024) {
                    #pragma unroll
                    for (int nt = 0; nt < 4; nt++) {
                        int n = n0 + nt * 16 + c;
                        int h = n >> 6, dd = n & 63;
                        ((unsigned short*)qbb)[(((size_t)b * Hz + h) * Tz + t) * DQK + dd] =
                            f2bf(acc[mq][nt][r] * QK_SCALE2);
                    }
                } else {
                    float inv = __expf(-(float)c * 0.5756462732485114f);
                    float ang = (float)t * inv;
                    float cs = cosf(ang), sn = sinf(ang);
                    #pragma unroll
                    for (int np = 0; np < 4; np += 2) {
                        float v0 = acc[mq][np][r] * QK_SCALE2;
                        float v1 = acc[mq][np + 1][r] * QK_SCALE2;
                        int col0 = (n0 - 1024) + np * 16;
                        int h = col0 >> 5;
                        size_t base = (((size_t)b * Hz + h) * Tz + t) * DQK + 64;
                        qbb[base + c]      = f2bf(v0 * cs - v1 * sn);
                        qbb[base + c + 16] = f2bf(v1 * cs + v0 * sn);
                    }
                }
            } else {
                if (n0 < 1024) {
                    #pragma unroll
                    for (int nt = 0; nt < 4; nt++) {
                        int n = n0 + nt * 16 + c;
                        int h = n >> 6, dd = n & 63;
                        kbb[(((size_t)b * Hz + h) * Tz + t) * DQK + dd] = f2bf(acc[mq][nt][r]);
                    }
                } else {
                    #pragma unroll
                    for (int nt = 0; nt < 4; nt++) {
                        int n = (n0 - 1024) + nt * 16 + c;
                        int h = n >> 6, dd = n & 63;
                        vtb[(((size_t)b * Hz + h) * 64 + dd) * Tz + t] = f2bf(acc[mq][nt][r]);
                    }
                }
            }
        }
    }
}

// ---------------------------------------------------------------------------
// RMSNorm over rows of 256: fp32 in, bf16 out, gain g. One wave per row.
// ---------------------------------------------------------------------------
__global__ __launch_bounds__(256) void rmsnorm_k(const float* __restrict__ kv,
                                                 const float* __restrict__ g,
                                                 unsigned short* __restrict__ outb)
{
    int row = blockIdx.x * 4 + (threadIdx.x >> 6);
    int lane = threadIdx.x & 63;
    const float* p = kv + (size_t)row * 256;
    float v[4];
    float ss = 0.f;
    #pragma unroll
    for (int i = 0; i < 4; i++) { v[i] = p[lane + i * 64]; ss += v[i] * v[i]; }
    #pragma unroll
    for (int o = 32; o > 0; o >>= 1) ss += __shfl_xor(ss, o);
    float r = rsqrtf(ss * (1.f / 256.f) + 1e-6f);
    #pragma unroll
    for (int i = 0; i < 4; i++)
        outb[(size_t)row * 256 + lane + i * 64] = f2bf(v[i] * r * g[lane + i * 64]);
}

// ---------------------------------------------------------------------------
// Pipelined MFMA flash attention (r9/r15 version — session best, 84.4us).
// Swapped QK^T (lane owns one q-row), exp2 softmax, defer-max, K
// double-buffered in LDS (one syncthreads per tile), V direct from L2,
// P through per-wave LDS strip via cvt_pk. launch_bounds(256,3): VGPR 84.
// ---------------------------------------------------------------------------
#define PSTR 72

__global__ __launch_bounds__(256, 3) void attn_mfma(
    const unsigned short* __restrict__ q,
    const unsigned short* __restrict__ k,
    const unsigned short* __restrict__ vt,
    unsigned short* __restrict__ o)
{
    __shared__ __attribute__((aligned(16))) unsigned short Ks[2][64 * 96];
    __shared__ __attribute__((aligned(16))) unsigned short Ps[4][16 * PSTR];

    int tid = threadIdx.x;
    int lane = tid & 63;
    int w = tid >> 6;
    int c = lane & 15, g = lane >> 4;

    int s = blockIdx.x;                        // 0..1023
    int bh = s & 31;
    int j = s >> 5;                            // 0..31
    int qt = (j < 16) ? (31 - j) : (j - 16);   // per-CU balanced
    int q0 = qt * 64;
    int ntiles = qt + 1;

    const unsigned short* qb = q + (size_t)bh * Tz * DQK;
    const unsigned short* kb = k + (size_t)bh * Tz * DQK;
    const unsigned short* vb = vt + (size_t)bh * 64 * Tz;
    unsigned short* ps = &Ps[w][0];

    // staging geometry: 768 16B-chunks = 64 rows x 12 chunks; 3 per thread
    int soff[3], sidx[3];
    #pragma unroll
    for (int i = 0; i < 3; i++) {
        int id2 = tid + i * 256;
        int srow = id2 / 12, sc8 = id2 % 12;
        soff[i] = srow * DQK + sc8 * 8;                       // global u16 offset
        sidx[i] = (srow * 96 + sc8 * 8) ^ ((srow & 7) << 3);  // swizzled LDS u16
    }

    // Q fragments (B operand)
    short8 qf[3];
    {
        const unsigned short* qrow = qb + (size_t)(q0 + w * 16 + c) * DQK;
        #pragma unroll
        for (int kc = 0; kc < 3; kc++)
            qf[kc] = *(const short8*)(qrow + kc * 32 + g * 8);
    }

    // stage tile 0
    short8 kreg[3];
    #pragma unroll
    for (int i = 0; i < 3; i++)
        kreg[i] = *(const short8*)&kb[soff[i]];
    #pragma unroll
    for (int i = 0; i < 3; i++)
        *(short8*)&Ks[0][sidx[i]] = kreg[i];
    __syncthreads();

    f32x4 oacc[4] = {};
    float mrun = -1e30f, lrun = 0.f;

    for (int t = 0; t < ntiles; t++) {
        int cur = t & 1;
        int kt0 = t * 64;
        bool more = (t + 1) < ntiles;

        // prefetch next K tile -> regs
        if (more) {
            #pragma unroll
            for (int i = 0; i < 3; i++)
                kreg[i] = *(const short8*)&kb[(size_t)(kt0 + 64) * DQK + soff[i]];
        }
        // issue V fragment loads now; consumed after softmax
        short8 vf[2][4];
        #pragma unroll
        for (int kc2 = 0; kc2 < 2; kc2++)
            #pragma unroll
            for (int nt = 0; nt < 4; nt++)
                vf[kc2][nt] = *(const short8*)&vb[(size_t)(nt * 16 + c) * Tz + kt0 + kc2 * 32 + g * 8];

        // S^T = K @ Q^T (swapped operands)
        f32x4 sacc[4] = {};
        __builtin_amdgcn_s_setprio(1);
        #pragma unroll
        for (int kc = 0; kc < 3; kc++) {
            #pragma unroll
            for (int nt = 0; nt < 4; nt++) {
                short8 kf = *(const short8*)&Ks[cur][((nt * 16 + c) * 96 + kc * 32 + g * 8) ^ ((c & 7) << 3)];
                sacc[nt] = __builtin_amdgcn_mfma_f32_16x16x32_bf16(kf, qf[kc], sacc[nt], 0, 0, 0);
            }
        }
        __builtin_amdgcn_s_setprio(0);

        // causal mask (diagonal tile): k = nt*16+g*4+r, q = w*16+c
        if (kt0 == q0) {
            #pragma unroll
            for (int nt = 0; nt < 4; nt++)
                #pragma unroll
                for (int r = 0; r < 4; r++)
                    if (nt * 16 + g * 4 + r > w * 16 + c)
                        sacc[nt][r] = -1e30f;
        }

        // row max (lane's q-row = c)
        float pm = sacc[0][0];
        #pragma unroll
        for (int nt = 0; nt < 4; nt++)
            #pragma unroll
            for (int r = 0; r < 4; r++)
                pm = fmaxf(pm, sacc[nt][r]);
        pm = fmaxf(pm, __shfl_xor(pm, 16));
        pm = fmaxf(pm, __shfl_xor(pm, 32));

        bool need = pm > mrun + THR2;
        if (__ballot(need)) {
            float mn = fmaxf(mrun, pm);
            float sc = exp2f(mrun - mn);
            mrun = mn;
            float rs = 0.f;
            #pragma unroll
            for (int nt = 0; nt < 4; nt++)
                #pragma unroll
                for (int r = 0; r < 4; r++) {
                    sacc[nt][r] = exp2f(sacc[nt][r] - mrun);
                    rs += sacc[nt][r];
                }
            rs += __shfl_xor(rs, 16);
            rs += __shfl_xor(rs, 32);
            lrun = lrun * sc + rs;
            float scr[4];
            #pragma unroll
            for (int r = 0; r < 4; r++) scr[r] = __shfl(sc, g * 4 + r);
            #pragma unroll
            for (int nt = 0; nt < 4; nt++)
                #pragma unroll
                for (int r = 0; r < 4; r++)
                    oacc[nt][r] *= scr[r];
        } else {
            float rs = 0.f;
            #pragma unroll
            for (int nt = 0; nt < 4; nt++)
                #pragma unroll
                for (int r = 0; r < 4; r++) {
                    sacc[nt][r] = exp2f(sacc[nt][r] - mrun);
                    rs += sacc[nt][r];
                }
            rs += __shfl_xor(rs, 16);
            rs += __shfl_xor(rs, 32);
            lrun += rs;
        }

        // P -> LDS: pack pairs via cvt_pk
        #pragma unroll
        for (int nt = 0; nt < 4; nt++)
            #pragma unroll
            for (int rp = 0; rp < 2; rp++) {
                unsigned w32;
                asm("v_cvt_pk_bf16_f32 %0, %1, %2"
                    : "=v"(w32) : "v"(sacc[nt][2 * rp]), "v"(sacc[nt][2 * rp + 1]));
                *(unsigned*)&ps[c * PSTR + nt * 16 + g * 4 + 2 * rp] = w32;
            }
        __builtin_amdgcn_wave_barrier();

        // O += P @ V
        __builtin_amdgcn_s_setprio(1);
        #pragma unroll
        for (int kc2 = 0; kc2 < 2; kc2++) {
            short8 pf = *(const short8*)&ps[c * PSTR + kc2 * 32 + g * 8];
            #pragma unroll
            for (int nt = 0; nt < 4; nt++)
                oacc[nt] = __builtin_amdgcn_mfma_f32_16x16x32_bf16(pf, vf[kc2][nt], oacc[nt], 0, 0, 0);
        }
        __builtin_amdgcn_s_setprio(0);
        __builtin_amdgcn_wave_barrier();

        // write next K buffer, one barrier per tile
        if (more) {
            #pragma unroll
            for (int i = 0; i < 3; i++)
                *(short8*)&Ks[1 - cur][sidx[i]] = kreg[i];
            __syncthreads();
        }
    }

    // epilogue: fetch per-row l from owner lanes, write bf16 heads buffer
    float lr[4];
    #pragma unroll
    for (int r = 0; r < 4; r++) lr[r] = __shfl(lrun, g * 4 + r);
    #pragma unroll
    for (int nt = 0; nt < 4; nt++)
        #pragma unroll
        for (int r = 0; r < 4; r++)
            o[((size_t)bh * Tz + q0 + w * 16 + g * 4 + r) * 64 + nt * 16 + c] =
                f2bf(oacc[nt][r] / lr[r]);
}

// ---------------------------------------------------------------------------
extern "C" void kernel_launch(void* const* d_in, const int* in_sizes, int n_in,
                              void* d_out, int out_size, void* d_ws, size_t ws_size,
                              hipStream_t stream)
{
    const float* x       = (const float*)d_in[0];
    const float* W_kv    = (const float*)d_in[1];
    const float* g_kv    = (const float*)d_in[2];
    const float* W_kdec  = (const float*)d_in[3];
    const float* W_vdec  = (const float*)d_in[4];
    const float* W_q     = (const float*)d_in[5];
    const float* W_qdec  = (const float*)d_in[6];
    const float* W_krope = (const float*)d_in[7];
    const float* W_qrope = (const float*)d_in[8];
    const float* W_o     = (const float*)d_in[9];
    float* out = (float*)d_out;

    float* kv_f32 = (float*)d_ws;                           // 4096*256 f32
    unsigned short* us = (unsigned short*)(kv_f32 + (size_t)Mz * KVR);
    unsigned short* x_bf  = us;               us += (size_t)Mz * Cz;
    unsigned short* kv_bf = us;               us += (size_t)Mz * KVR;
    unsigned short* qc_bf = us;               us += (size_t)Mz * QR;
    unsigned short* qbb   = us;               us += (size_t)BHT * DQK;
    unsigned short* kbb   = us;               us += (size_t)BHT * DQK;
    unsigned short* vtb   = us;               us += (size_t)BHT * 64;
    unsigned short* ob    = us;               us += (size_t)BHT * 64;
    unsigned short* wc1 = us;                 us += (size_t)1280 * Cz;  // [W_kv|W_q|W_krope]^T
    unsigned short* wc2 = us;                 us += (size_t)1536 * QR;  // [W_qdec|W_qrope]^T
    unsigned short* wc3 = us;                 us += (size_t)2048 * KVR; // [W_kdec|W_vdec]^T
    unsigned short* woT = us;                 us += (size_t)Cz * Cz;    // W_o^T

    dim3 blk(256);

    conv_f32_bf16<<<dim3((Mz*Cz)/1024), blk, 0, stream>>>(x, x_bf, Mz*Cz);

    TDesc8 td;
    const float* tsrc[8] = {W_kv, W_q, W_krope, W_qdec, W_qrope, W_kdec, W_vdec, W_o};
    unsigned short* tdst[8] = {
        wc1, wc1 + (size_t)256 * Cz, wc1 + (size_t)768 * Cz,
        wc2, wc2 + (size_t)1024 * QR,
        wc3, wc3 + (size_t)1024 * KVR,
        woT };
    int tK[8] = {Cz, Cz, Cz, QR, QR, KVR, KVR, Cz};
    int tN[8] = {KVR, QR, Hz*Rz, Hz*Dz, Hz*Rz, Hz*Dz, Hz*Dz, Cz};
    int cum = 0;
    td.tile0[0] = 0;
    for (int i = 0; i < 8; i++) {
        td.src[i] = tsrc[i]; td.dst[i] = tdst[i]; td.K[i] = tK[i]; td.N[i] = tN[i];
        cum += (tK[i] / 32) * (tN[i] / 32);
        td.tile0[i + 1] = cum;
    }
    transpose_all<<<dim3(cum), blk, 0, stream>>>(td);

    // G1: x @ [W_kv | W_q | W_krope]  (N=1280, K=1024)
    gemm1w<1><<<dim3(Mz/64, 1280/64), dim3(64), 0, stream>>>(
        x_bf, wc1, kv_f32, qc_bf, kbb, Cz, 1.f);
    // RMSNorm -> bf16
    rmsnorm_k<<<dim3(Mz/4), blk, 0, stream>>>(kv_f32, g_kv, kv_bf);
    // G2+G3 merged (q decode + kv decode)
    gemm1w23<<<dim3(Mz/64, 56), dim3(64), 0, stream>>>(
        qc_bf, wc2, qbb, kv_bf, wc3, kbb, vtb);
    // Pipelined flash attention -> bf16 heads buffer
    attn_mfma<<<dim3(1024), blk, 0, stream>>>(qbb, kbb, vtb, ob);
    // G4: heads(ob) @ W_o -> out fp32 (N=1024, K=1024)
    gemm1w<4><<<dim3(Mz/64, Cz/64), dim3(64), 0, stream>>>(
        ob, woT, out, nullptr, nullptr, Cz, 1.f);
}